// Round 1
// baseline (1134.503 us; speedup 1.0000x reference)
//
#include <hip/hip_runtime.h>

// Problem constants (fixed by the reference)
#define N_SIG (1 << 23)   // 8388608 input/output length
#define N2    (1 << 24)   // padded FFT length
#define LM    (N2 / 4)    // constant l*m product for all Stockham stages

// ---------------------------------------------------------------------------
// pack: z[i] = a_pad[i] + i * x_pad[i]  (zero-padded to N2)
// ---------------------------------------------------------------------------
__global__ void pack_kernel(const float* __restrict__ a,
                            const float* __restrict__ x,
                            float2* __restrict__ z) {
    int i = blockIdx.x * blockDim.x + threadIdx.x;
    float re = 0.0f, im = 0.0f;
    if (i < N_SIG) { re = a[i]; im = x[i]; }
    z[i] = make_float2(re, im);
}

// ---------------------------------------------------------------------------
// One Stockham radix-4 DIF stage (natural-order output after all stages).
//   for l = N2/4 .. 1 (/=4), m = 1 .. N2/4 (*=4):
//     y[k + m*(4j+q)] = w^q * (radix-4 butterfly of x[k + m*(j + q*l)])
//   w = exp(-2*pi*i * j / (4l))
// ---------------------------------------------------------------------------
__global__ void fft4_stage(const float2* __restrict__ X,
                           float2* __restrict__ Y,
                           int l, int mshift) {
    int t = blockIdx.x * blockDim.x + threadIdx.x;  // [0, N2/4)
    int m = 1 << mshift;
    int k = t & (m - 1);
    int j = t >> mshift;
    int base = k + (j << mshift);        // k + m*j

    float2 c0 = X[base];
    float2 c1 = X[base + LM];
    float2 c2 = X[base + 2 * LM];
    float2 c3 = X[base + 3 * LM];

    // radix-4 DIF butterfly
    float2 d0 = make_float2(c0.x + c2.x, c0.y + c2.y);
    float2 d1 = make_float2(c0.x - c2.x, c0.y - c2.y);
    float2 d2 = make_float2(c1.x + c3.x, c1.y + c3.y);
    // d3 = -i * (c1 - c3)
    float2 d3 = make_float2(c1.y - c3.y, -(c1.x - c3.x));

    // twiddle w1 = exp(-i * (pi/2) * j / l); j/l in [0,1) exactly representable
    float ang = -1.5707963267948966f * ((float)j / (float)l);
    float s, c;
    sincosf(ang, &s, &c);
    float2 w1 = make_float2(c, s);
    float2 w2 = make_float2(c * c - s * s, 2.0f * c * s);
    float2 w3 = make_float2(w1.x * w2.x - w1.y * w2.y,
                            w1.x * w2.y + w1.y * w2.x);

    float2 e0 = make_float2(d0.x + d2.x, d0.y + d2.y);
    float2 t1 = make_float2(d1.x + d3.x, d1.y + d3.y);
    float2 t2 = make_float2(d0.x - d2.x, d0.y - d2.y);
    float2 t3 = make_float2(d1.x - d3.x, d1.y - d3.y);

    float2 e1 = make_float2(w1.x * t1.x - w1.y * t1.y,
                            w1.x * t1.y + w1.y * t1.x);
    float2 e2 = make_float2(w2.x * t2.x - w2.y * t2.y,
                            w2.x * t2.y + w2.y * t2.x);
    float2 e3 = make_float2(w3.x * t3.x - w3.y * t3.y,
                            w3.x * t3.y + w3.y * t3.x);

    int ob = k + (j << (mshift + 2));    // k + 4*m*j
    Y[ob]         = e0;
    Y[ob + m]     = e1;
    Y[ob + 2 * m] = e2;
    Y[ob + 3 * m] = e3;
}

// ---------------------------------------------------------------------------
// pointwise: V[k] = conj(FA[k]*FX[k]) = (i/4) * (conj(Z[k])^2 - Z[N2-k]^2)
// (so that fft(V).real / N2 = ifft(FA*FX).real)
// ---------------------------------------------------------------------------
__global__ void pointwise_kernel(const float2* __restrict__ Z,
                                 float2* __restrict__ V) {
    int k = blockIdx.x * blockDim.x + threadIdx.x;
    float2 zk = Z[k];
    float2 zr = Z[(N2 - k) & (N2 - 1)];

    // conj(zk)^2
    float cx = zk.x, cy = -zk.y;
    float2 a2 = make_float2(cx * cx - cy * cy, 2.0f * cx * cy);
    // zr^2
    float2 b2 = make_float2(zr.x * zr.x - zr.y * zr.y, 2.0f * zr.x * zr.y);

    float dx = a2.x - b2.x;
    float dy = a2.y - b2.y;
    // (i/4) * (dx + i dy) = 0.25 * (-dy + i dx)
    V[k] = make_float2(-0.25f * dy, 0.25f * dx);
}

// ---------------------------------------------------------------------------
// final: y[i] = Re(Y[i]) / N2, first N_SIG elements
// ---------------------------------------------------------------------------
__global__ void final_kernel(const float2* __restrict__ Y,
                             float* __restrict__ out) {
    int i = blockIdx.x * blockDim.x + threadIdx.x;
    if (i < N_SIG) out[i] = Y[i].x * (1.0f / (float)N2);
}

extern "C" void kernel_launch(void* const* d_in, const int* in_sizes, int n_in,
                              void* d_out, int out_size, void* d_ws, size_t ws_size,
                              hipStream_t stream) {
    const float* a = (const float*)d_in[0];
    const float* x = (const float*)d_in[1];
    float* out = (float*)d_out;

    float2* buf0 = (float2*)d_ws;          // 128 MB
    float2* buf1 = buf0 + N2;              // 128 MB

    dim3 blk(256);

    // 1. pack z = a_pad + i*x_pad
    pack_kernel<<<N2 / 256, blk, 0, stream>>>(a, x, buf0);

    // 2. forward FFT (12 radix-4 Stockham stages), buf0 <-> buf1
    {
        float2* src = buf0;
        float2* dst = buf1;
        int l = N2 / 4, mshift = 0;
        for (int s = 0; s < 12; s++) {
            fft4_stage<<<(N2 / 4) / 256, blk, 0, stream>>>(src, dst, l, mshift);
            float2* tmp = src; src = dst; dst = tmp;
            l >>= 2; mshift += 2;
        }
        // result in buf0 (even number of swaps)
    }

    // 3. pointwise product (Hermitian split + conj for inverse-via-forward)
    pointwise_kernel<<<N2 / 256, blk, 0, stream>>>(buf0, buf1);

    // 4. forward FFT of V (12 stages), buf1 <-> buf0
    {
        float2* src = buf1;
        float2* dst = buf0;
        int l = N2 / 4, mshift = 0;
        for (int s = 0; s < 12; s++) {
            fft4_stage<<<(N2 / 4) / 256, blk, 0, stream>>>(src, dst, l, mshift);
            float2* tmp = src; src = dst; dst = tmp;
            l >>= 2; mshift += 2;
        }
        // result in buf1
    }

    // 5. extract real part / N2
    final_kernel<<<(N_SIG + 255) / 256, blk, 0, stream>>>(buf1, out);
}

// Round 2
// 281.049 us; speedup vs baseline: 4.0367x; 4.0367x over previous
//
#include <hip/hip_runtime.h>

#define N_SIG (1 << 23)   // 8388608
#define N2    (1 << 24)   // padded FFT length = 256^3

// ---------------------------------------------------------------------------
// complex helpers
// ---------------------------------------------------------------------------
__device__ __forceinline__ float2 cadd(float2 a, float2 b) { return make_float2(a.x + b.x, a.y + b.y); }
__device__ __forceinline__ float2 csub(float2 a, float2 b) { return make_float2(a.x - b.x, a.y - b.y); }
__device__ __forceinline__ float2 cmul(float2 a, float2 b) {
    return make_float2(fmaf(a.x, b.x, -(a.y * b.y)), fmaf(a.x, b.y, a.y * b.x));
}
__device__ __forceinline__ float2 mulnegi(float2 a) { return make_float2(a.y, -a.x); }  // -i*a

// exp(-2*pi*i*f), f in [0,1) given in revolutions (v_sin/v_cos take revolutions)
__device__ __forceinline__ float2 twid(float f) {
    float s, c;
#if __has_builtin(__builtin_amdgcn_sinf) && __has_builtin(__builtin_amdgcn_cosf)
    s = __builtin_amdgcn_sinf(f);
    c = __builtin_amdgcn_cosf(f);
#else
    __sincosf(6.28318530717958647693f * f, &s, &c);
#endif
    return make_float2(c, -s);
}

// radix-4 DIF butterfly (negative-exponent DFT), outputs r=0..3
__device__ __forceinline__ void bfly4(float2 c0, float2 c1, float2 c2, float2 c3,
                                      float2& e0, float2& e1, float2& e2, float2& e3) {
    float2 d0 = cadd(c0, c2), d1 = csub(c0, c2);
    float2 d2 = cadd(c1, c3), d3 = mulnegi(csub(c1, c3));
    e0 = cadd(d0, d2); e1 = cadd(d1, d3); e2 = csub(d0, d2); e3 = csub(d1, d3);
}

// 16-point DFT, natural order in/out (two Stockham radix-4 stages, all static idx)
__device__ __forceinline__ void fft16(float2 v[16]) {
    const float C1 = 0.92387953251128675613f;
    const float S1 = 0.38268343236508977173f;
    const float RH = 0.70710678118654752440f;
    const float2 W1 = make_float2( C1, -S1);
    const float2 W2 = make_float2( RH, -RH);
    const float2 W3 = make_float2( S1, -C1);
    const float2 W6 = make_float2(-RH, -RH);
    const float2 W9 = make_float2(-C1,  S1);
    float2 t[16];
    { float2 e0,e1,e2,e3; bfly4(v[0],v[4],v[8],v[12], e0,e1,e2,e3);
      t[0]=e0; t[1]=e1; t[2]=e2; t[3]=e3; }
    { float2 e0,e1,e2,e3; bfly4(v[1],v[5],v[9],v[13], e0,e1,e2,e3);
      t[4]=e0; t[5]=cmul(e1,W1); t[6]=cmul(e2,W2); t[7]=cmul(e3,W3); }
    { float2 e0,e1,e2,e3; bfly4(v[2],v[6],v[10],v[14], e0,e1,e2,e3);
      t[8]=e0; t[9]=cmul(e1,W2); t[10]=mulnegi(e2); t[11]=cmul(e3,W6); }
    { float2 e0,e1,e2,e3; bfly4(v[3],v[7],v[11],v[15], e0,e1,e2,e3);
      t[12]=e0; t[13]=cmul(e1,W3); t[14]=cmul(e2,W6); t[15]=cmul(e3,W9); }
    { float2 e0,e1,e2,e3; bfly4(t[0],t[4],t[8],t[12], e0,e1,e2,e3);
      v[0]=e0; v[4]=e1; v[8]=e2; v[12]=e3; }
    { float2 e0,e1,e2,e3; bfly4(t[1],t[5],t[9],t[13], e0,e1,e2,e3);
      v[1]=e0; v[5]=e1; v[9]=e2; v[13]=e3; }
    { float2 e0,e1,e2,e3; bfly4(t[2],t[6],t[10],t[14], e0,e1,e2,e3);
      v[2]=e0; v[6]=e1; v[10]=e2; v[14]=e3; }
    { float2 e0,e1,e2,e3; bfly4(t[3],t[7],t[11],t[15], e0,e1,e2,e3);
      v[3]=e0; v[7]=e1; v[11]=e2; v[15]=e3; }
}

// ---------------------------------------------------------------------------
// One radix-256 Stockham stage. N2 = 256^3, three stages per FFT:
//   stage A: (l=65536, m=1)     out[256 j + r]
//   stage B: (l=256,   m=256)   out[k + 65536 j + 256 r]
//   stage C: (l=1,     m=65536) out[k + 65536 r]
// All stages read in[base + 65536 q], q = u1 + 16 u2, 256-pt DFT over q done as
// FFT16(u2) -> W256^{u1 v1} -> LDS transpose -> FFT16(u1) -> outer twiddle
// w^r = exp(-2 pi i j r / (256 l)).
// MODE: 0=fwd A (pack fused), 1=fwd B, 2=fwd C, 3=inv A (pointwise fused),
//       4=inv B, 5=inv C (real extract + 1/N2 fused)
// ---------------------------------------------------------------------------
template<int MODE>
__global__ __launch_bounds__(512, 4)
void fft_pass(const float* __restrict__ ga, const float* __restrict__ gx,
              const float2* __restrict__ gin, float2* __restrict__ gout,
              float* __restrict__ goutr) {
    __shared__ float2 tile[32 * 256];   // 64 KB
    const int t    = threadIdx.x;
    const int row  = t & 31;
    const int slot = t >> 5;            // u1 (layer1) / v1 (layer2), in [0,16)
    const int blk  = blockIdx.x;
    const int mask = row & 15;          // LDS XOR swizzle (bank-conflict floor)

    int jt;                             // outer-twiddle j index
    float2 v[16];

    if constexpr (MODE == 0) {          // fwd stage A, pack fused (zero-pad q>=128)
        int j = blk * 32 + row;
        jt = j;
        #pragma unroll
        for (int u2 = 0; u2 < 16; ++u2) {
            if (u2 < 8) {
                int g = j + ((slot + 16 * u2) << 16);   // < N_SIG exactly
                v[u2] = make_float2(ga[g], gx[g]);
            } else {
                v[u2] = make_float2(0.f, 0.f);
            }
        }
    } else if constexpr (MODE == 3) {   // inv stage A, pointwise fused
        int j = blk * 32 + row;
        jt = j;
        #pragma unroll
        for (int u2 = 0; u2 < 16; ++u2) {
            int g  = j + ((slot + 16 * u2) << 16);
            int gm = (N2 - g) & (N2 - 1);
            float2 zk = gin[g];
            float2 zr = gin[gm];
            // V = (i/4)*(conj(zk)^2 - zr^2)
            float cx = zk.x, cy = -zk.y;
            float a2x = cx * cx - cy * cy, a2y = 2.f * cx * cy;
            float b2x = zr.x * zr.x - zr.y * zr.y, b2y = 2.f * zr.x * zr.y;
            float dx = a2x - b2x, dy = a2y - b2y;
            v[u2] = make_float2(-0.25f * dy, 0.25f * dx);
        }
    } else if constexpr (MODE == 1 || MODE == 4) {   // stage B
        int jB = blk >> 3;
        int k0 = (blk & 7) * 32;
        int bi = (k0 + row) + (jB << 8);
        jt = jB;
        #pragma unroll
        for (int u2 = 0; u2 < 16; ++u2)
            v[u2] = gin[bi + ((slot + 16 * u2) << 16)];
    } else {                            // stage C (MODE 2, 5)
        int bi = blk * 32 + row;
        jt = 0;
        #pragma unroll
        for (int u2 = 0; u2 < 16; ++u2)
            v[u2] = gin[bi + ((slot + 16 * u2) << 16)];
    }

    // ---- layer 1: FFT16 over u2, then inter-layer twiddle W256^{u1 v1'} ----
    fft16(v);
    #pragma unroll
    for (int r = 1; r < 16; ++r)
        v[r] = cmul(v[r], twid((float)(slot * r) * (1.0f / 256.0f)));
    #pragma unroll
    for (int r = 0; r < 16; ++r)
        tile[row * 256 + ((slot + 16 * r) ^ mask)] = v[r];
    __syncthreads();

    // ---- layer 2: gather G[u1, v1], FFT16 over u1 ----
    float2 w[16];
    #pragma unroll
    for (int u1 = 0; u1 < 16; ++u1)
        w[u1] = tile[row * 256 + ((u1 + (slot << 4)) ^ mask)];
    __syncthreads();
    fft16(w);

    // ---- outer twiddle w^r, r = v1 + 16 v2 ----
    if constexpr (MODE == 0 || MODE == 3) {          // denom 2^24, jt*r < 2^24 exact
        #pragma unroll
        for (int v2 = 0; v2 < 16; ++v2) {
            int r = slot + 16 * v2;
            w[v2] = cmul(w[v2], twid((float)(jt * r) * (1.0f / 16777216.0f)));
        }
    } else if constexpr (MODE == 1 || MODE == 4) {   // denom 65536
        #pragma unroll
        for (int v2 = 0; v2 < 16; ++v2) {
            int r = slot + 16 * v2;
            w[v2] = cmul(w[v2], twid((float)(jt * r) * (1.0f / 65536.0f)));
        }
    } // stage C: j=0, no twiddle

    // ---- stage LDS, then cooperative coalesced global store ----
    if constexpr (MODE == 5) {
        // real extract: keep r < 128 only, scale by 1/N2
        float* ftile = (float*)tile;
        #pragma unroll
        for (int v2 = 0; v2 < 8; ++v2) {
            int r = slot + 16 * v2;                   // < 128
            ftile[row * 128 + (r ^ mask)] = w[v2].x * (1.0f / 16777216.0f);
        }
        __syncthreads();
        int k0 = blk * 32;
        #pragma unroll
        for (int i = 0; i < 8; ++i) {
            int s = t + 512 * i;                      // 32*128 floats
            int r = s >> 5, kl = s & 31;
            goutr[k0 + kl + (r << 16)] = ftile[kl * 128 + (r ^ (kl & 15))];
        }
    } else {
        #pragma unroll
        for (int v2 = 0; v2 < 16; ++v2)
            tile[row * 256 + ((slot + (v2 << 4)) ^ mask)] = w[v2];
        __syncthreads();
        if constexpr (MODE == 0 || MODE == 3) {
            int base = blk * 8192;                    // out[256 j + r] is linear
            #pragma unroll
            for (int i = 0; i < 16; ++i) {
                int s = t + 512 * i;
                int rr = s >> 8, c = s & 255;
                gout[base + s] = tile[rr * 256 + (c ^ (rr & 15))];
            }
        } else if constexpr (MODE == 1 || MODE == 4) {
            int jB = blk >> 3, k0 = (blk & 7) * 32;
            int base = k0 + (jB << 16);               // out = base + kl + 256 r
            #pragma unroll
            for (int i = 0; i < 16; ++i) {
                int s = t + 512 * i;
                int r = s >> 5, kl = s & 31;
                gout[base + kl + (r << 8)] = tile[kl * 256 + (r ^ (kl & 15))];
            }
        } else {                                      // MODE 2: out = k0 + kl + 65536 r
            int k0 = blk * 32;
            #pragma unroll
            for (int i = 0; i < 16; ++i) {
                int s = t + 512 * i;
                int r = s >> 5, kl = s & 31;
                gout[k0 + kl + (r << 16)] = tile[kl * 256 + (r ^ (kl & 15))];
            }
        }
    }
}

extern "C" void kernel_launch(void* const* d_in, const int* in_sizes, int n_in,
                              void* d_out, int out_size, void* d_ws, size_t ws_size,
                              hipStream_t stream) {
    const float* a = (const float*)d_in[0];
    const float* x = (const float*)d_in[1];
    float* out = (float*)d_out;

    float2* buf0 = (float2*)d_ws;       // 128 MB
    float2* buf1 = buf0 + N2;           // 128 MB

    dim3 g(2048), b(512);
    // forward FFT of z = a + i*x  (pack fused into stage A)
    fft_pass<0><<<g, b, 0, stream>>>(a, x, nullptr, buf0, nullptr);
    fft_pass<1><<<g, b, 0, stream>>>(nullptr, nullptr, buf0, buf1, nullptr);
    fft_pass<2><<<g, b, 0, stream>>>(nullptr, nullptr, buf1, buf0, nullptr);
    // inverse-via-forward FFT of V = conj(FA*FX) (pointwise fused into stage A)
    fft_pass<3><<<g, b, 0, stream>>>(nullptr, nullptr, buf0, buf1, nullptr);
    fft_pass<4><<<g, b, 0, stream>>>(nullptr, nullptr, buf1, buf0, nullptr);
    // stage C + real extract + 1/N2
    fft_pass<5><<<g, b, 0, stream>>>(nullptr, nullptr, buf0, nullptr, out);
}